// Round 1
// baseline (411.830 us; speedup 1.0000x reference)
//
#include <hip/hip_runtime.h>
#include <hip/hip_bf16.h>
#include <math.h>

#define NN 131072
#define HD 256

typedef __bf16 bf16;
typedef __attribute__((ext_vector_type(8))) __bf16 bf16x8;
typedef __attribute__((ext_vector_type(4))) __bf16 bf16x4;
typedef __attribute__((ext_vector_type(4))) float f32x4;

__device__ __forceinline__ float silu_f(float x) { return x / (1.f + __expf(-x)); }

__device__ __forceinline__ float bfu2f(unsigned int lo16) {
    unsigned int u = lo16 << 16;
    return __builtin_bit_cast(float, u);
}
__device__ __forceinline__ unsigned short f2bfu(float f) {
    bf16 b = (bf16)f;
    return __builtin_bit_cast(unsigned short, b);
}

// A-tile (LDS, bf16, row stride LDA) x packed-B (global bf16x8) -> acc[4][4]
// Wave computes 64 rows x 64 cols (cols [wave*64, wave*64+64)).
template<int KSTEPS, int LDA>
__device__ __forceinline__ void mm_tile(const bf16* Xl, const bf16x8* __restrict__ Bp,
                                        int wave, int lane, f32x4 acc[4][4]) {
    const int lrow = lane & 15, lkhi = lane >> 4;
    #pragma unroll
    for (int ks = 0; ks < KSTEPS; ++ks) {
        bf16x8 a[4];
        #pragma unroll
        for (int r = 0; r < 4; ++r)
            a[r] = *(const bf16x8*)&Xl[(r * 16 + lrow) * LDA + ks * 32 + lkhi * 8];
        #pragma unroll
        for (int c = 0; c < 4; ++c) {
            bf16x8 b = Bp[(ks * 16 + wave * 4 + c) * 64 + lane];
            #pragma unroll
            for (int r = 0; r < 4; ++r)
                acc[r][c] = __builtin_amdgcn_mfma_f32_16x16x32_bf16(a[r], b, acc[r][c], 0, 0, 0);
        }
    }
}

// ---------------- weight packing ----------------
// P[((ks*16+cb)*64+lane)*8+j] = W[ks*32 + (lane>>4)*8 + j][cb*16 + (lane&15)]
__device__ __forceinline__ void packW(const float* __restrict__ W, bf16* __restrict__ P, int idx) {
    int j  = idx & 7;
    int ln = (idx >> 3) & 63;
    int cb = (idx >> 9) & 15;
    int ks = idx >> 13;
    int k = ks * 32 + ((ln >> 4) << 3) + j;
    int n = (cb << 4) + (ln & 15);
    P[idx] = (bf16)W[k * HD + n];
}

__global__ void pack_kernel(const float* __restrict__ ew1, const float* __restrict__ ew2,
                            const float* __restrict__ pw1, const float* __restrict__ nw1,
                            const float* __restrict__ nw2, const float* __restrict__ pw2,
                            bf16* __restrict__ ew1p, bf16* __restrict__ ew2p,
                            bf16* __restrict__ pw1p, bf16* __restrict__ nw1p,
                            bf16* __restrict__ nw2p, float* __restrict__ pw2T) {
    int t = blockIdx.x * 256 + threadIdx.x;
    if (t < 131072) { packW(ew1, ew1p, t); return; }   // ew1 rows 0..511
    t -= 131072;
    if (t < 65536)  { packW(ew2, ew2p, t); return; }
    t -= 65536;
    if (t < 65536)  { packW(pw1, pw1p, t); return; }
    t -= 65536;
    if (t < 131072) { packW(nw1, nw1p, t); return; }
    t -= 131072;
    if (t < 65536)  { packW(nw2, nw2p, t); return; }
    t -= 65536;
    if (t < 768) {  // pw2T[c][k] = pw2[k][c]
        int c = t >> 8, k = t & 255;
        pw2T[t] = pw2[k * 3 + c];
    }
}

// ---------------- edge kernel ----------------
// 64 edges per block. edge_feat = [h[e] | h[e+1] | dist] handled as:
//   K<256 -> X row r; K in [256,512) -> X row r+1; K=512 -> fp32 rank-1 update.
__global__ __launch_bounds__(256, 2) void edge_kernel(
    const float* __restrict__ h, const float* __restrict__ pos,
    const float* __restrict__ ew1, const float* __restrict__ eb1,
    const float* __restrict__ eb2, const float* __restrict__ pb1,
    const bf16x8* __restrict__ ew1p, const bf16x8* __restrict__ ew2p,
    const bf16x8* __restrict__ pw1p, const float* __restrict__ pw2T,
    bf16* __restrict__ ea_g, float* __restrict__ dp_g) {
    __shared__ bf16 X[65 * 264];   // h rows (staging) then reused as T0 (64x264)
    __shared__ bf16 T1[64 * 264];
    __shared__ float dist_s[64];

    const int tid = threadIdx.x;
    const int lane = tid & 63, wave = tid >> 6;
    const int lrow = lane & 15, lkhi = lane >> 4;
    const int e0 = blockIdx.x * 64;

    // stage h rows e0..e0+64 (bf16)
    for (int idx = tid; idx < 65 * 64; idx += 256) {
        int r = idx >> 6, c4 = (idx & 63) << 2;
        int gr = e0 + r;
        float4 v = make_float4(0.f, 0.f, 0.f, 0.f);
        if (gr < NN) v = *(const float4*)&h[(size_t)gr * HD + c4];
        bf16x4 b;
        b[0] = (bf16)v.x; b[1] = (bf16)v.y; b[2] = (bf16)v.z; b[3] = (bf16)v.w;
        *(bf16x4*)&X[r * 264 + c4] = b;
    }
    if (tid < 64) {
        int e = e0 + tid;
        float d = 0.f;
        if (e < NN - 1) {
            float dx = pos[3 * e + 3] - pos[3 * e];
            float dy = pos[3 * e + 4] - pos[3 * e + 1];
            float dz = pos[3 * e + 5] - pos[3 * e + 2];
            d = sqrtf(dx * dx + dy * dy + dz * dz);
        }
        dist_s[tid] = d;
    }
    __syncthreads();

    f32x4 acc[4][4];
    #pragma unroll
    for (int r = 0; r < 4; ++r)
        #pragma unroll
        for (int c = 0; c < 4; ++c) acc[r][c] = (f32x4)0.f;

    // phase 1: t1 = silu(edge_feat @ ew1 + eb1)
    #pragma unroll
    for (int ks = 0; ks < 16; ++ks) {
        const int rb = (ks >= 8) ? 1 : 0;
        const int kk = ks * 32 + lkhi * 8 - rb * 256;
        bf16x8 a[4];
        #pragma unroll
        for (int r = 0; r < 4; ++r)
            a[r] = *(const bf16x8*)&X[(r * 16 + lrow + rb) * 264 + kk];
        #pragma unroll
        for (int c = 0; c < 4; ++c) {
            bf16x8 b = ew1p[(ks * 16 + wave * 4 + c) * 64 + lane];
            #pragma unroll
            for (int r = 0; r < 4; ++r)
                acc[r][c] = __builtin_amdgcn_mfma_f32_16x16x32_bf16(a[r], b, acc[r][c], 0, 0, 0);
        }
    }
    float bias1[4], wlast[4];
    #pragma unroll
    for (int c = 0; c < 4; ++c) {
        int col = (wave * 4 + c) * 16 + lrow;
        bias1[c] = eb1[col];
        wlast[c] = ew1[512 * HD + col];  // dist column of ew1
    }
    __syncthreads();  // all phase-1 X reads done before T0 overlay
    #pragma unroll
    for (int r = 0; r < 4; ++r)
        #pragma unroll
        for (int c = 0; c < 4; ++c)
            #pragma unroll
            for (int q = 0; q < 4; ++q) {
                int row = r * 16 + lkhi * 4 + q;
                int col = (wave * 4 + c) * 16 + lrow;
                float v = acc[r][c][q] + dist_s[row] * wlast[c] + bias1[c];
                X[row * 264 + col] = (bf16)silu_f(v);  // T0 = t1
            }
    __syncthreads();

    // phase 2: ea = t1 @ ew2 + eb2  -> T1 (+ global)
    #pragma unroll
    for (int r = 0; r < 4; ++r)
        #pragma unroll
        for (int c = 0; c < 4; ++c) acc[r][c] = (f32x4)0.f;
    mm_tile<8, 264>(X, ew2p, wave, lane, acc);
    float bias2[4];
    #pragma unroll
    for (int c = 0; c < 4; ++c) bias2[c] = eb2[(wave * 4 + c) * 16 + lrow];
    #pragma unroll
    for (int r = 0; r < 4; ++r)
        #pragma unroll
        for (int c = 0; c < 4; ++c)
            #pragma unroll
            for (int q = 0; q < 4; ++q) {
                int row = r * 16 + lkhi * 4 + q;
                int col = (wave * 4 + c) * 16 + lrow;
                T1[row * 264 + col] = (bf16)(acc[r][c][q] + bias2[c]);
            }
    __syncthreads();

    // coalesced copy T1 -> ea_g
    for (int idx = tid; idx < 64 * 128; idx += 256) {
        int r = idx >> 7, cu = idx & 127;
        ((unsigned int*)&ea_g[(size_t)(e0 + r) * HD])[cu] = ((const unsigned int*)&T1[r * 264])[cu];
    }

    // phase 3: t3 = silu(ea @ pw1 + pb1) -> T0
    #pragma unroll
    for (int r = 0; r < 4; ++r)
        #pragma unroll
        for (int c = 0; c < 4; ++c) acc[r][c] = (f32x4)0.f;
    mm_tile<8, 264>(T1, pw1p, wave, lane, acc);
    float bias3[4];
    #pragma unroll
    for (int c = 0; c < 4; ++c) bias3[c] = pb1[(wave * 4 + c) * 16 + lrow];
    #pragma unroll
    for (int r = 0; r < 4; ++r)
        #pragma unroll
        for (int c = 0; c < 4; ++c)
            #pragma unroll
            for (int q = 0; q < 4; ++q) {
                int row = r * 16 + lkhi * 4 + q;
                int col = (wave * 4 + c) * 16 + lrow;
                X[row * 264 + col] = (bf16)silu_f(acc[r][c][q] + bias3[c]);
            }
    __syncthreads();

    // phase 4: delta_pos = t3 @ pw2 (vector, 3 cols)
    if (tid < 192) {
        int row = tid & 63, col = tid >> 6;
        float s = 0.f;
        #pragma unroll 4
        for (int k = 0; k < 256; k += 8) {
            bf16x8 t = *(const bf16x8*)&X[row * 264 + k];
            #pragma unroll
            for (int j = 0; j < 8; ++j)
                s += (float)t[j] * pw2T[col * 256 + k + j];
        }
        dp_g[(size_t)(e0 + row) * 3 + col] = s;
    }
}

// ---------------- node kernel ----------------
__global__ __launch_bounds__(256, 2) void node_kernel(
    const float* __restrict__ h, const float* __restrict__ pos,
    const float* __restrict__ nb1, const float* __restrict__ nb2,
    const bf16x8* __restrict__ nw1p, const bf16x8* __restrict__ nw2p,
    const bf16* __restrict__ ea_g, const float* __restrict__ dp_g,
    float* __restrict__ h_out, float* __restrict__ pos_out) {
    __shared__ bf16 X[64 * 520];  // h_cat; reused (stride 264) as T0

    const int tid = threadIdx.x;
    const int lane = tid & 63, wave = tid >> 6;
    const int lrow = lane & 15, lkhi = lane >> 4;
    const int i0 = blockIdx.x * 64;

    // pos head (independent of LDS phases)
    if (tid < 192) {
        int row = tid & 63, col = tid >> 6;
        int i = i0 + row;
        float dpi = (i < NN - 1) ? dp_g[(size_t)i * 3 + col] : 0.f;
        float dpm = (i > 0) ? dp_g[(size_t)(i - 1) * 3 + col] : 0.f;
        pos_out[(size_t)i * 3 + col] = pos[(size_t)i * 3 + col] + 0.1f * (dpi - dpm);
    }

    // stage h -> X cols 0..255
    for (int idx = tid; idx < 64 * 64; idx += 256) {
        int r = idx >> 6, c4 = (idx & 63) << 2;
        float4 v = *(const float4*)&h[(size_t)(i0 + r) * HD + c4];
        bf16x4 b;
        b[0] = (bf16)v.x; b[1] = (bf16)v.y; b[2] = (bf16)v.z; b[3] = (bf16)v.w;
        *(bf16x4*)&X[r * 520 + c4] = b;
    }
    // stage node_update = ea[i] + ea[i-1] -> X cols 256..511
    for (int idx = tid; idx < 64 * 128; idx += 256) {
        int r = idx >> 7, cu = idx & 127;
        int i = i0 + r;
        unsigned int au = (i < NN - 1) ? ((const unsigned int*)&ea_g[(size_t)i * HD])[cu] : 0u;
        unsigned int bu = (i > 0) ? ((const unsigned int*)&ea_g[(size_t)(i - 1) * HD])[cu] : 0u;
        float lo = bfu2f(au & 0xffffu) + bfu2f(bu & 0xffffu);
        float hi = bfu2f(au >> 16) + bfu2f(bu >> 16);
        unsigned int pk = (unsigned int)f2bfu(lo) | ((unsigned int)f2bfu(hi) << 16);
        ((unsigned int*)&X[r * 520 + 256])[cu] = pk;
    }
    __syncthreads();

    f32x4 acc[4][4];
    #pragma unroll
    for (int r = 0; r < 4; ++r)
        #pragma unroll
        for (int c = 0; c < 4; ++c) acc[r][c] = (f32x4)0.f;
    mm_tile<16, 520>(X, nw1p, wave, lane, acc);
    float b1[4];
    #pragma unroll
    for (int c = 0; c < 4; ++c) b1[c] = nb1[(wave * 4 + c) * 16 + lrow];
    __syncthreads();
    #pragma unroll
    for (int r = 0; r < 4; ++r)
        #pragma unroll
        for (int c = 0; c < 4; ++c)
            #pragma unroll
            for (int q = 0; q < 4; ++q) {
                int row = r * 16 + lkhi * 4 + q;
                int col = (wave * 4 + c) * 16 + lrow;
                X[row * 264 + col] = (bf16)silu_f(acc[r][c][q] + b1[c]);  // T0
            }
    __syncthreads();

    #pragma unroll
    for (int r = 0; r < 4; ++r)
        #pragma unroll
        for (int c = 0; c < 4; ++c) acc[r][c] = (f32x4)0.f;
    mm_tile<8, 264>(X, nw2p, wave, lane, acc);
    float b2[4];
    #pragma unroll
    for (int c = 0; c < 4; ++c) b2[c] = nb2[(wave * 4 + c) * 16 + lrow];
    #pragma unroll
    for (int r = 0; r < 4; ++r)
        #pragma unroll
        for (int c = 0; c < 4; ++c)
            #pragma unroll
            for (int q = 0; q < 4; ++q) {
                int row = r * 16 + lkhi * 4 + q;
                int col = (wave * 4 + c) * 16 + lrow;
                h_out[(size_t)(i0 + row) * HD + col] = acc[r][c][q] + b2[c];
            }
}

// ---------------- launch ----------------
extern "C" void kernel_launch(void* const* d_in, const int* in_sizes, int n_in,
                              void* d_out, int out_size, void* d_ws, size_t ws_size,
                              hipStream_t stream) {
    const float* h   = (const float*)d_in[0];
    const float* pos = (const float*)d_in[1];
    const float* ew1 = (const float*)d_in[2];
    const float* eb1 = (const float*)d_in[3];
    const float* ew2 = (const float*)d_in[4];
    const float* eb2 = (const float*)d_in[5];
    const float* pw1 = (const float*)d_in[6];
    const float* pb1 = (const float*)d_in[7];
    const float* pw2 = (const float*)d_in[8];
    const float* nw1 = (const float*)d_in[9];
    const float* nb1 = (const float*)d_in[10];
    const float* nw2 = (const float*)d_in[11];
    const float* nb2 = (const float*)d_in[12];

    char* ws = (char*)d_ws;
    bf16*  ea  = (bf16*)ws;                       // 131072*256*2 = 67108864 B
    float* dp  = (float*)(ws + 67108864);         // 131072*3*4   = 1572864 B
    char*  wsw = ws + 68681728;
    bf16*  ew1p = (bf16*)(wsw);                   // 262144 B
    bf16*  ew2p = (bf16*)(wsw + 262144);          // 131072 B
    bf16*  pw1p = (bf16*)(wsw + 393216);          // 131072 B
    bf16*  nw1p = (bf16*)(wsw + 524288);          // 262144 B
    bf16*  nw2p = (bf16*)(wsw + 786432);          // 131072 B
    float* pw2T = (float*)(wsw + 917504);         // 3072 B

    float* out = (float*)d_out;
    float* h_out = out;
    float* pos_out = out + (size_t)NN * HD;

    pack_kernel<<<1795, 256, 0, stream>>>(ew1, ew2, pw1, nw1, nw2, pw2,
                                          ew1p, ew2p, pw1p, nw1p, nw2p, pw2T);
    edge_kernel<<<2048, 256, 0, stream>>>(h, pos, ew1, eb1, eb2, pb1,
                                          (const bf16x8*)ew1p, (const bf16x8*)ew2p,
                                          (const bf16x8*)pw1p, pw2T, ea, dp);
    node_kernel<<<2048, 256, 0, stream>>>(h, pos, nb1, nb2,
                                          (const bf16x8*)nw1p, (const bf16x8*)nw2p,
                                          ea, dp, h_out, pos_out);
}

// Round 2
// 388.337 us; speedup vs baseline: 1.0605x; 1.0605x over previous
//
#include <hip/hip_runtime.h>
#include <hip/hip_bf16.h>
#include <math.h>

#define NN 131072
#define HD 256

typedef __bf16 bf16;
typedef __attribute__((ext_vector_type(8))) __bf16 bf16x8;
typedef __attribute__((ext_vector_type(4))) __bf16 bf16x4;
typedef __attribute__((ext_vector_type(4))) float f32x4;

__device__ __forceinline__ float silu_f(float x) { return x / (1.f + __expf(-x)); }

// A-tile (LDS bf16, row stride LDA) x packed-B (global bf16x8, weight k-step offset bk0)
// Wave computes 64 rows x 64 cols (cols [wave*64, wave*64+64)).
template<int KSTEPS, int LDA>
__device__ __forceinline__ void mm_tile(const bf16* Xl, int bk0, const bf16x8* __restrict__ Bp,
                                        int wave, int lane, f32x4 acc[4][4]) {
    const int lrow = lane & 15, lkhi = lane >> 4;
    #pragma unroll
    for (int ks = 0; ks < KSTEPS; ++ks) {
        bf16x8 a[4];
        #pragma unroll
        for (int r = 0; r < 4; ++r)
            a[r] = *(const bf16x8*)&Xl[(r * 16 + lrow) * LDA + ks * 32 + lkhi * 8];
        #pragma unroll
        for (int c = 0; c < 4; ++c) {
            bf16x8 b = Bp[((bk0 + ks) * 16 + wave * 4 + c) * 64 + lane];
            #pragma unroll
            for (int r = 0; r < 4; ++r)
                acc[r][c] = __builtin_amdgcn_mfma_f32_16x16x32_bf16(a[r], b, acc[r][c], 0, 0, 0);
        }
    }
}

// ---------------- weight packing ----------------
// P[((ks*16+cb)*64+lane)*8+j] = W[ks*32 + (lane>>4)*8 + j][cb*16 + (lane&15)]
__device__ __forceinline__ void packW(const float* __restrict__ W, bf16* __restrict__ P, int idx) {
    int j  = idx & 7;
    int ln = (idx >> 3) & 63;
    int cb = (idx >> 9) & 15;
    int ks = idx >> 13;
    int k = ks * 32 + ((ln >> 4) << 3) + j;
    int n = (cb << 4) + (ln & 15);
    P[idx] = (bf16)W[k * HD + n];
}

__global__ void pack_kernel(const float* __restrict__ ew1, const float* __restrict__ ew2,
                            const float* __restrict__ pw1, const float* __restrict__ nw1,
                            const float* __restrict__ nw2,
                            bf16* __restrict__ ew1p, bf16* __restrict__ ew2p,
                            bf16* __restrict__ pw1p, bf16* __restrict__ nw1p,
                            bf16* __restrict__ nw2p) {
    int t = blockIdx.x * 256 + threadIdx.x;
    if (t < 131072) { packW(ew1, ew1p, t); return; }   // ew1 rows 0..511
    t -= 131072;
    if (t < 65536)  { packW(ew2, ew2p, t); return; }
    t -= 65536;
    if (t < 65536)  { packW(pw1, pw1p, t); return; }
    t -= 65536;
    if (t < 131072) { packW(nw1, nw1p, t); return; }
    t -= 131072;
    if (t < 65536)  { packW(nw2, nw2p, t); return; }
}

// ---------------- edge kernel ----------------
// 64 edges/block, single LDS buffer (in-place phase chain) -> 37.6KB -> 4 blocks/CU.
__global__ __launch_bounds__(256, 4) void edge_kernel(
    const float* __restrict__ h, const float* __restrict__ pos,
    const float* __restrict__ ew1, const float* __restrict__ eb1,
    const float* __restrict__ eb2, const float* __restrict__ pb1,
    const float* __restrict__ pw2,
    const bf16x8* __restrict__ ew1p, const bf16x8* __restrict__ ew2p,
    const bf16x8* __restrict__ pw1p,
    bf16* __restrict__ ea_g, float* __restrict__ dp_g) {
    __shared__ bf16 X[65 * 264];          // h rows -> t1 -> ea (in place)
    __shared__ float dist_s[64];
    __shared__ float dp_s[4][64][3];

    const int tid = threadIdx.x;
    const int lane = tid & 63, wave = tid >> 6;
    const int lrow = lane & 15, lkhi = lane >> 4;
    const int e0 = blockIdx.x * 64;

    // stage h rows e0..e0+64 (bf16)
    for (int idx = tid; idx < 65 * 64; idx += 256) {
        int r = idx >> 6, c4 = (idx & 63) << 2;
        int gr = e0 + r;
        float4 v = make_float4(0.f, 0.f, 0.f, 0.f);
        if (gr < NN) v = *(const float4*)&h[(size_t)gr * HD + c4];
        bf16x4 b;
        b[0] = (bf16)v.x; b[1] = (bf16)v.y; b[2] = (bf16)v.z; b[3] = (bf16)v.w;
        *(bf16x4*)&X[r * 264 + c4] = b;
    }
    if (tid < 64) {
        int e = e0 + tid;
        float d = 0.f;
        if (e < NN - 1) {
            float dx = pos[3 * e + 3] - pos[3 * e];
            float dy = pos[3 * e + 4] - pos[3 * e + 1];
            float dz = pos[3 * e + 5] - pos[3 * e + 2];
            d = sqrtf(dx * dx + dy * dy + dz * dz);
        }
        dist_s[tid] = d;
    }
    __syncthreads();

    f32x4 acc[4][4];
    #pragma unroll
    for (int r = 0; r < 4; ++r)
        #pragma unroll
        for (int c = 0; c < 4; ++c) acc[r][c] = (f32x4)0.f;

    // phase 1: t1 = silu(edge_feat @ ew1 + eb1); K halves via row shift rb
    #pragma unroll
    for (int ks = 0; ks < 16; ++ks) {
        const int rb = (ks >= 8) ? 1 : 0;
        const int kk = ks * 32 + lkhi * 8 - rb * 256;
        bf16x8 a[4];
        #pragma unroll
        for (int r = 0; r < 4; ++r)
            a[r] = *(const bf16x8*)&X[(r * 16 + lrow + rb) * 264 + kk];
        #pragma unroll
        for (int c = 0; c < 4; ++c) {
            bf16x8 b = ew1p[(ks * 16 + wave * 4 + c) * 64 + lane];
            #pragma unroll
            for (int r = 0; r < 4; ++r)
                acc[r][c] = __builtin_amdgcn_mfma_f32_16x16x32_bf16(a[r], b, acc[r][c], 0, 0, 0);
        }
    }
    float bias1[4], wlast[4], w2l[4][3];
    #pragma unroll
    for (int c = 0; c < 4; ++c) {
        int col = (wave * 4 + c) * 16 + lrow;
        bias1[c] = eb1[col];
        wlast[c] = ew1[512 * HD + col];       // dist row of ew1
        #pragma unroll
        for (int x = 0; x < 3; ++x) w2l[c][x] = pw2[col * 3 + x];
    }
    __syncthreads();  // all phase-1 reads of X done
    #pragma unroll
    for (int r = 0; r < 4; ++r)
        #pragma unroll
        for (int c = 0; c < 4; ++c)
            #pragma unroll
            for (int q = 0; q < 4; ++q) {
                int row = r * 16 + lkhi * 4 + q;
                int col = (wave * 4 + c) * 16 + lrow;
                float v = acc[r][c][q] + dist_s[row] * wlast[c] + bias1[c];
                X[row * 264 + col] = (bf16)silu_f(v);  // t1 in place
            }
    __syncthreads();

    // phase 2: ea = t1 @ ew2 + eb2 (in place)
    #pragma unroll
    for (int r = 0; r < 4; ++r)
        #pragma unroll
        for (int c = 0; c < 4; ++c) acc[r][c] = (f32x4)0.f;
    mm_tile<8, 264>(X, 0, ew2p, wave, lane, acc);
    float bias2[4];
    #pragma unroll
    for (int c = 0; c < 4; ++c) bias2[c] = eb2[(wave * 4 + c) * 16 + lrow];
    __syncthreads();
    #pragma unroll
    for (int r = 0; r < 4; ++r)
        #pragma unroll
        for (int c = 0; c < 4; ++c)
            #pragma unroll
            for (int q = 0; q < 4; ++q) {
                int row = r * 16 + lkhi * 4 + q;
                int col = (wave * 4 + c) * 16 + lrow;
                X[row * 264 + col] = (bf16)(acc[r][c][q] + bias2[c]);
            }
    __syncthreads();

    // ea -> global (coalesced from LDS)
    for (int idx = tid; idx < 64 * 128; idx += 256) {
        int r = idx >> 7, cu = idx & 127;
        ((unsigned int*)&ea_g[(size_t)(e0 + r) * HD])[cu] = ((const unsigned int*)&X[r * 264])[cu];
    }

    // phase 3: t3 = silu(ea @ pw1 + pb1) kept in regs; dp = t3 @ pw2 from regs
    #pragma unroll
    for (int r = 0; r < 4; ++r)
        #pragma unroll
        for (int c = 0; c < 4; ++c) acc[r][c] = (f32x4)0.f;
    mm_tile<8, 264>(X, 0, pw1p, wave, lane, acc);
    float bias3[4];
    #pragma unroll
    for (int c = 0; c < 4; ++c) bias3[c] = pb1[(wave * 4 + c) * 16 + lrow];

    #pragma unroll
    for (int r = 0; r < 4; ++r) {
        float red[12];
        #pragma unroll
        for (int q = 0; q < 4; ++q) {
            float t3v[4];
            #pragma unroll
            for (int c = 0; c < 4; ++c) t3v[c] = silu_f(acc[r][c][q] + bias3[c]);
            #pragma unroll
            for (int x = 0; x < 3; ++x) {
                float s = 0.f;
                #pragma unroll
                for (int c = 0; c < 4; ++c) s += t3v[c] * w2l[c][x];
                red[q * 3 + x] = s;
            }
        }
        #pragma unroll
        for (int i = 0; i < 12; ++i) {
            float v = red[i];
            v += __shfl_xor(v, 1);
            v += __shfl_xor(v, 2);
            v += __shfl_xor(v, 4);
            v += __shfl_xor(v, 8);
            red[i] = v;
        }
        if (lrow == 0) {
            #pragma unroll
            for (int q = 0; q < 4; ++q)
                #pragma unroll
                for (int x = 0; x < 3; ++x)
                    dp_s[wave][r * 16 + lkhi * 4 + q][x] = red[q * 3 + x];
        }
    }
    __syncthreads();
    if (tid < 192) {
        int row = tid / 3, x = tid - row * 3;
        float s = dp_s[0][row][x] + dp_s[1][row][x] + dp_s[2][row][x] + dp_s[3][row][x];
        dp_g[(size_t)(e0 + row) * 3 + x] = s;
    }
}

// ---------------- node kernel ----------------
// 64 nodes/block. Only ea halo staged (65x264 = 34.3KB -> 4 blocks/CU).
// nu = ea[i-1]+ea[i] via linearity: two MFMA passes, A-row offsets 0/1.
// h half: A-fragments read directly from global fp32 (L3-resident).
__global__ __launch_bounds__(256, 4) void node_kernel(
    const float* __restrict__ h, const float* __restrict__ pos,
    const float* __restrict__ nb1, const float* __restrict__ nb2,
    const bf16x8* __restrict__ nw1p, const bf16x8* __restrict__ nw2p,
    const bf16* __restrict__ ea_g, const float* __restrict__ dp_g,
    float* __restrict__ h_out, float* __restrict__ pos_out) {
    __shared__ bf16 EA[65 * 264];   // ea rows n0-1..n0+63 -> t4 (in place)

    const int tid = threadIdx.x;
    const int lane = tid & 63, wave = tid >> 6;
    const int lrow = lane & 15, lkhi = lane >> 4;
    const int n0 = blockIdx.x * 64;

    // pos head (global-only)
    if (tid < 192) {
        int row = tid & 63, col = tid >> 6;
        int i = n0 + row;
        float dpi = (i < NN - 1) ? dp_g[(size_t)i * 3 + col] : 0.f;
        float dpm = (i > 0) ? dp_g[(size_t)(i - 1) * 3 + col] : 0.f;
        pos_out[(size_t)i * 3 + col] = pos[(size_t)i * 3 + col] + 0.1f * (dpi - dpm);
    }

    // stage ea halo: EA row t = ea_g[n0-1+t], zero outside [0, NN-2]
    for (int idx = tid; idx < 65 * 128; idx += 256) {
        int t = idx >> 7, cu = idx & 127;
        int er = n0 - 1 + t;
        unsigned int v = (er >= 0 && er <= NN - 2) ? ((const unsigned int*)&ea_g[(size_t)er * HD])[cu] : 0u;
        ((unsigned int*)&EA[t * 264])[cu] = v;
    }
    __syncthreads();

    f32x4 acc[4][4];
    #pragma unroll
    for (int r = 0; r < 4; ++r)
        #pragma unroll
        for (int c = 0; c < 4; ++c) acc[r][c] = (f32x4)0.f;

    // node P1, h half (weight ks 0..7): fragments straight from global fp32
    #pragma unroll
    for (int ks = 0; ks < 8; ++ks) {
        bf16x8 a[4];
        #pragma unroll
        for (int r = 0; r < 4; ++r) {
            const float4* hp = (const float4*)&h[(size_t)(n0 + r * 16 + lrow) * HD + ks * 32 + lkhi * 8];
            float4 v0 = hp[0], v1 = hp[1];
            bf16x8 t;
            t[0] = (bf16)v0.x; t[1] = (bf16)v0.y; t[2] = (bf16)v0.z; t[3] = (bf16)v0.w;
            t[4] = (bf16)v1.x; t[5] = (bf16)v1.y; t[6] = (bf16)v1.z; t[7] = (bf16)v1.w;
            a[r] = t;
        }
        #pragma unroll
        for (int c = 0; c < 4; ++c) {
            bf16x8 b = nw1p[(ks * 16 + wave * 4 + c) * 64 + lane];
            #pragma unroll
            for (int r = 0; r < 4; ++r)
                acc[r][c] = __builtin_amdgcn_mfma_f32_16x16x32_bf16(a[r], b, acc[r][c], 0, 0, 0);
        }
    }
    // node P1, nu half (weight ks 8..15): ea[i-1] (offset 0) + ea[i] (offset 1)
    mm_tile<8, 264>(EA, 8, nw1p, wave, lane, acc);
    mm_tile<8, 264>(EA + 264, 8, nw1p, wave, lane, acc);

    float b1[4];
    #pragma unroll
    for (int c = 0; c < 4; ++c) b1[c] = nb1[(wave * 4 + c) * 16 + lrow];
    __syncthreads();  // all P1 reads of EA done
    #pragma unroll
    for (int r = 0; r < 4; ++r)
        #pragma unroll
        for (int c = 0; c < 4; ++c)
            #pragma unroll
            for (int q = 0; q < 4; ++q) {
                int row = r * 16 + lkhi * 4 + q;
                int col = (wave * 4 + c) * 16 + lrow;
                EA[row * 264 + col] = (bf16)silu_f(acc[r][c][q] + b1[c]);  // t4 in place
            }
    __syncthreads();

    #pragma unroll
    for (int r = 0; r < 4; ++r)
        #pragma unroll
        for (int c = 0; c < 4; ++c) acc[r][c] = (f32x4)0.f;
    mm_tile<8, 264>(EA, 0, nw2p, wave, lane, acc);
    float b2[4];
    #pragma unroll
    for (int c = 0; c < 4; ++c) b2[c] = nb2[(wave * 4 + c) * 16 + lrow];
    #pragma unroll
    for (int r = 0; r < 4; ++r)
        #pragma unroll
        for (int c = 0; c < 4; ++c)
            #pragma unroll
            for (int q = 0; q < 4; ++q) {
                int row = r * 16 + lkhi * 4 + q;
                int col = (wave * 4 + c) * 16 + lrow;
                h_out[(size_t)(n0 + row) * HD + col] = acc[r][c][q] + b2[c];
            }
}

// ---------------- launch ----------------
extern "C" void kernel_launch(void* const* d_in, const int* in_sizes, int n_in,
                              void* d_out, int out_size, void* d_ws, size_t ws_size,
                              hipStream_t stream) {
    const float* h   = (const float*)d_in[0];
    const float* pos = (const float*)d_in[1];
    const float* ew1 = (const float*)d_in[2];
    const float* eb1 = (const float*)d_in[3];
    const float* ew2 = (const float*)d_in[4];
    const float* eb2 = (const float*)d_in[5];
    const float* pw1 = (const float*)d_in[6];
    const float* pb1 = (const float*)d_in[7];
    const float* pw2 = (const float*)d_in[8];
    const float* nw1 = (const float*)d_in[9];
    const float* nb1 = (const float*)d_in[10];
    const float* nw2 = (const float*)d_in[11];
    const float* nb2 = (const float*)d_in[12];

    char* ws = (char*)d_ws;
    bf16*  ea  = (bf16*)ws;                       // 131072*256*2 = 67108864 B
    float* dp  = (float*)(ws + 67108864);         // 131072*3*4   = 1572864 B
    char*  wsw = ws + 68681728;
    bf16*  ew1p = (bf16*)(wsw);                   // 262144 B
    bf16*  ew2p = (bf16*)(wsw + 262144);          // 131072 B
    bf16*  pw1p = (bf16*)(wsw + 393216);          // 131072 B
    bf16*  nw1p = (bf16*)(wsw + 524288);          // 262144 B
    bf16*  nw2p = (bf16*)(wsw + 786432);          // 131072 B

    float* out = (float*)d_out;
    float* h_out = out;
    float* pos_out = out + (size_t)NN * HD;

    pack_kernel<<<1792, 256, 0, stream>>>(ew1, ew2, pw1, nw1, nw2,
                                          ew1p, ew2p, pw1p, nw1p, nw2p);
    edge_kernel<<<2048, 256, 0, stream>>>(h, pos, ew1, eb1, eb2, pb1, pw2,
                                          (const bf16x8*)ew1p, (const bf16x8*)ew2p,
                                          (const bf16x8*)pw1p, ea, dp);
    node_kernel<<<2048, 256, 0, stream>>>(h, pos, nb1, nb2,
                                          (const bf16x8*)nw1p, (const bf16x8*)nw2p,
                                          ea, dp, h_out, pos_out);
}

// Round 3
// 375.285 us; speedup vs baseline: 1.0974x; 1.0348x over previous
//
#include <hip/hip_runtime.h>
#include <hip/hip_bf16.h>
#include <math.h>

#define NN 131072
#define HD 256

typedef __bf16 bf16;
typedef __attribute__((ext_vector_type(8))) __bf16 bf16x8;
typedef __attribute__((ext_vector_type(4))) __bf16 bf16x4;
typedef __attribute__((ext_vector_type(4))) float f32x4;

__device__ __forceinline__ float silu_f(float x) { return x / (1.f + __expf(-x)); }

__device__ __forceinline__ float bfu2f(unsigned int lo16) {
    unsigned int u = lo16 << 16;
    return __builtin_bit_cast(float, u);
}
__device__ __forceinline__ unsigned short f2bfu(float f) {
    bf16 b = (bf16)f;
    return __builtin_bit_cast(unsigned short, b);
}

// A-tile (LDS bf16, row stride LDA) x packed-B (global bf16x8, weight k-step offset bk0)
// Wave computes 64 rows x 64 cols (cols [wave*64, wave*64+64)).
template<int KSTEPS, int LDA>
__device__ __forceinline__ void mm_tile(const bf16* Xl, int bk0, const bf16x8* __restrict__ Bp,
                                        int wave, int lane, f32x4 acc[4][4]) {
    const int lrow = lane & 15, lkhi = lane >> 4;
    #pragma unroll
    for (int ks = 0; ks < KSTEPS; ++ks) {
        bf16x8 a[4];
        #pragma unroll
        for (int r = 0; r < 4; ++r)
            a[r] = *(const bf16x8*)&Xl[(r * 16 + lrow) * LDA + ks * 32 + lkhi * 8];
        #pragma unroll
        for (int c = 0; c < 4; ++c) {
            bf16x8 b = Bp[((bk0 + ks) * 16 + wave * 4 + c) * 64 + lane];
            #pragma unroll
            for (int r = 0; r < 4; ++r)
                acc[r][c] = __builtin_amdgcn_mfma_f32_16x16x32_bf16(a[r], b, acc[r][c], 0, 0, 0);
        }
    }
}

// ---------------- weight packing ----------------
// P[((ks*16+cb)*64+lane)*8+j] = W[ks*32 + (lane>>4)*8 + j][cb*16 + (lane&15)]
__device__ __forceinline__ void packW(const float* __restrict__ W, bf16* __restrict__ P, int idx) {
    int j  = idx & 7;
    int ln = (idx >> 3) & 63;
    int cb = (idx >> 9) & 15;
    int ks = idx >> 13;
    int k = ks * 32 + ((ln >> 4) << 3) + j;
    int n = (cb << 4) + (ln & 15);
    P[idx] = (bf16)W[k * HD + n];
}

__global__ void pack_kernel(const float* __restrict__ ew1, const float* __restrict__ ew2,
                            const float* __restrict__ pw1, const float* __restrict__ nw1,
                            const float* __restrict__ nw2,
                            bf16* __restrict__ ew1p, bf16* __restrict__ ew2p,
                            bf16* __restrict__ pw1p, bf16* __restrict__ nw1p,
                            bf16* __restrict__ nw2p) {
    int t = blockIdx.x * 256 + threadIdx.x;
    if (t < 131072) { packW(ew1, ew1p, t); return; }   // ew1 rows 0..511
    t -= 131072;
    if (t < 65536)  { packW(ew2, ew2p, t); return; }
    t -= 65536;
    if (t < 65536)  { packW(pw1, pw1p, t); return; }
    t -= 65536;
    if (t < 131072) { packW(nw1, nw1p, t); return; }
    t -= 131072;
    if (t < 65536)  { packW(nw2, nw2p, t); return; }
}

// ---------------- edge kernel ----------------
// 64 edges/block, single LDS buffer, 4 blocks/CU.
// Also computes p1 = h_tile @ nw1[0:256] (node P1 h-half) while h is staged.
__global__ __launch_bounds__(256, 4) void edge_kernel(
    const float* __restrict__ h, const float* __restrict__ pos,
    const float* __restrict__ ew1, const float* __restrict__ eb1,
    const float* __restrict__ eb2, const float* __restrict__ pb1,
    const float* __restrict__ pw2,
    const bf16x8* __restrict__ ew1p, const bf16x8* __restrict__ ew2p,
    const bf16x8* __restrict__ pw1p, const bf16x8* __restrict__ nw1p,
    bf16* __restrict__ ea_g, unsigned int* __restrict__ p1_g,
    float* __restrict__ dp_g) {
    __shared__ bf16 X[65 * 264];          // h rows -> t1 -> ea (in place)
    __shared__ float dist_s[64];
    __shared__ float dp_s[4][64][3];

    const int tid = threadIdx.x;
    const int lane = tid & 63, wave = tid >> 6;
    const int lrow = lane & 15, lkhi = lane >> 4;
    const int e0 = blockIdx.x * 64;

    // stage h rows e0..e0+64 (bf16)
    for (int idx = tid; idx < 65 * 64; idx += 256) {
        int r = idx >> 6, c4 = (idx & 63) << 2;
        int gr = e0 + r;
        float4 v = make_float4(0.f, 0.f, 0.f, 0.f);
        if (gr < NN) v = *(const float4*)&h[(size_t)gr * HD + c4];
        bf16x4 b;
        b[0] = (bf16)v.x; b[1] = (bf16)v.y; b[2] = (bf16)v.z; b[3] = (bf16)v.w;
        *(bf16x4*)&X[r * 264 + c4] = b;
    }
    if (tid < 64) {
        int e = e0 + tid;
        float d = 0.f;
        if (e < NN - 1) {
            float dx = pos[3 * e + 3] - pos[3 * e];
            float dy = pos[3 * e + 4] - pos[3 * e + 1];
            float dz = pos[3 * e + 5] - pos[3 * e + 2];
            d = sqrtf(dx * dx + dy * dy + dz * dz);
        }
        dist_s[tid] = d;
    }
    __syncthreads();

    f32x4 acc[4][4];

    // phase 0: p1 = h_tile @ nw1[0:256] -> p1_g (bf16 pairs, fragment layout)
    #pragma unroll
    for (int r = 0; r < 4; ++r)
        #pragma unroll
        for (int c = 0; c < 4; ++c) acc[r][c] = (f32x4)0.f;
    mm_tile<8, 264>(X, 0, nw1p, wave, lane, acc);
    {
        unsigned int* p1w = p1_g + ((size_t)blockIdx.x * 4 + wave) * 2048;
        #pragma unroll
        for (int r = 0; r < 4; ++r)
            #pragma unroll
            for (int c = 0; c < 4; ++c)
                #pragma unroll
                for (int qh = 0; qh < 2; ++qh) {
                    unsigned int pk = (unsigned int)f2bfu(acc[r][c][2 * qh]) |
                                      ((unsigned int)f2bfu(acc[r][c][2 * qh + 1]) << 16);
                    p1w[((r * 4 + c) * 2 + qh) * 64 + lane] = pk;
                }
    }

    // phase 1: t1 = silu(edge_feat @ ew1 + eb1); K halves via row shift rb
    #pragma unroll
    for (int r = 0; r < 4; ++r)
        #pragma unroll
        for (int c = 0; c < 4; ++c) acc[r][c] = (f32x4)0.f;
    #pragma unroll
    for (int ks = 0; ks < 16; ++ks) {
        const int rb = (ks >= 8) ? 1 : 0;
        const int kk = ks * 32 + lkhi * 8 - rb * 256;
        bf16x8 a[4];
        #pragma unroll
        for (int r = 0; r < 4; ++r)
            a[r] = *(const bf16x8*)&X[(r * 16 + lrow + rb) * 264 + kk];
        #pragma unroll
        for (int c = 0; c < 4; ++c) {
            bf16x8 b = ew1p[(ks * 16 + wave * 4 + c) * 64 + lane];
            #pragma unroll
            for (int r = 0; r < 4; ++r)
                acc[r][c] = __builtin_amdgcn_mfma_f32_16x16x32_bf16(a[r], b, acc[r][c], 0, 0, 0);
        }
    }
    float bias1[4], wlast[4], w2l[4][3];
    #pragma unroll
    for (int c = 0; c < 4; ++c) {
        int col = (wave * 4 + c) * 16 + lrow;
        bias1[c] = eb1[col];
        wlast[c] = ew1[512 * HD + col];       // dist row of ew1
        #pragma unroll
        for (int x = 0; x < 3; ++x) w2l[c][x] = pw2[col * 3 + x];
    }
    __syncthreads();  // all phase-0/1 reads of X done
    #pragma unroll
    for (int r = 0; r < 4; ++r)
        #pragma unroll
        for (int c = 0; c < 4; ++c)
            #pragma unroll
            for (int q = 0; q < 4; ++q) {
                int row = r * 16 + lkhi * 4 + q;
                int col = (wave * 4 + c) * 16 + lrow;
                float v = acc[r][c][q] + dist_s[row] * wlast[c] + bias1[c];
                X[row * 264 + col] = (bf16)silu_f(v);  // t1 in place
            }
    __syncthreads();

    // phase 2: ea = t1 @ ew2 + eb2 (in place)
    #pragma unroll
    for (int r = 0; r < 4; ++r)
        #pragma unroll
        for (int c = 0; c < 4; ++c) acc[r][c] = (f32x4)0.f;
    mm_tile<8, 264>(X, 0, ew2p, wave, lane, acc);
    float bias2[4];
    #pragma unroll
    for (int c = 0; c < 4; ++c) bias2[c] = eb2[(wave * 4 + c) * 16 + lrow];
    __syncthreads();
    #pragma unroll
    for (int r = 0; r < 4; ++r)
        #pragma unroll
        for (int c = 0; c < 4; ++c)
            #pragma unroll
            for (int q = 0; q < 4; ++q) {
                int row = r * 16 + lkhi * 4 + q;
                int col = (wave * 4 + c) * 16 + lrow;
                X[row * 264 + col] = (bf16)(acc[r][c][q] + bias2[c]);
            }
    __syncthreads();

    // ea -> global (coalesced from LDS)
    for (int idx = tid; idx < 64 * 128; idx += 256) {
        int r = idx >> 7, cu = idx & 127;
        ((unsigned int*)&ea_g[(size_t)(e0 + r) * HD])[cu] = ((const unsigned int*)&X[r * 264])[cu];
    }

    // phase 3: t3 = silu(ea @ pw1 + pb1) kept in regs; dp = t3 @ pw2 from regs
    #pragma unroll
    for (int r = 0; r < 4; ++r)
        #pragma unroll
        for (int c = 0; c < 4; ++c) acc[r][c] = (f32x4)0.f;
    mm_tile<8, 264>(X, 0, pw1p, wave, lane, acc);
    float bias3[4];
    #pragma unroll
    for (int c = 0; c < 4; ++c) bias3[c] = pb1[(wave * 4 + c) * 16 + lrow];

    #pragma unroll
    for (int r = 0; r < 4; ++r) {
        float red[12];
        #pragma unroll
        for (int q = 0; q < 4; ++q) {
            float t3v[4];
            #pragma unroll
            for (int c = 0; c < 4; ++c) t3v[c] = silu_f(acc[r][c][q] + bias3[c]);
            #pragma unroll
            for (int x = 0; x < 3; ++x) {
                float s = 0.f;
                #pragma unroll
                for (int c = 0; c < 4; ++c) s += t3v[c] * w2l[c][x];
                red[q * 3 + x] = s;
            }
        }
        #pragma unroll
        for (int i = 0; i < 12; ++i) {
            float v = red[i];
            v += __shfl_xor(v, 1);
            v += __shfl_xor(v, 2);
            v += __shfl_xor(v, 4);
            v += __shfl_xor(v, 8);
            red[i] = v;
        }
        if (lrow == 0) {
            #pragma unroll
            for (int q = 0; q < 4; ++q)
                #pragma unroll
                for (int x = 0; x < 3; ++x)
                    dp_s[wave][r * 16 + lkhi * 4 + q][x] = red[q * 3 + x];
        }
    }
    __syncthreads();
    if (tid < 192) {
        int row = tid / 3, x = tid - row * 3;
        float s = dp_s[0][row][x] + dp_s[1][row][x] + dp_s[2][row][x] + dp_s[3][row][x];
        dp_g[(size_t)(e0 + row) * 3 + x] = s;
    }
}

// ---------------- node kernel ----------------
// 64 nodes/block, single 65x264 LDS buffer (34.3KB -> 4 blocks/CU).
// P1 h-half comes precomputed from edge kernel (p1_g, fragment layout).
// nu = ea[i-1]+ea[i] via linearity: two MFMA passes over the ea halo tile.
__global__ __launch_bounds__(256, 4) void node_kernel(
    const float* __restrict__ pos,
    const float* __restrict__ nb1, const float* __restrict__ nb2,
    const bf16x8* __restrict__ nw1p, const bf16x8* __restrict__ nw2p,
    const bf16* __restrict__ ea_g, const unsigned int* __restrict__ p1_g,
    const float* __restrict__ dp_g,
    float* __restrict__ h_out, float* __restrict__ pos_out) {
    __shared__ bf16 EA[65 * 264];   // ea halo -> t4 -> h_out bf16 (in place)

    const int tid = threadIdx.x;
    const int lane = tid & 63, wave = tid >> 6;
    const int lrow = lane & 15, lkhi = lane >> 4;
    const int n0 = blockIdx.x * 64;

    // pos head (global-only)
    if (tid < 192) {
        int row = tid & 63, col = tid >> 6;
        int i = n0 + row;
        float dpi = (i < NN - 1) ? dp_g[(size_t)i * 3 + col] : 0.f;
        float dpm = (i > 0) ? dp_g[(size_t)(i - 1) * 3 + col] : 0.f;
        pos_out[(size_t)i * 3 + col] = pos[(size_t)i * 3 + col] + 0.1f * (dpi - dpm);
    }

    // stage ea halo: EA row t = ea_g[n0-1+t], zero outside [0, NN-2]
    for (int idx = tid; idx < 65 * 128; idx += 256) {
        int t = idx >> 7, cu = idx & 127;
        int er = n0 - 1 + t;
        unsigned int v = (er >= 0 && er <= NN - 2) ? ((const unsigned int*)&ea_g[(size_t)er * HD])[cu] : 0u;
        ((unsigned int*)&EA[t * 264])[cu] = v;
    }
    __syncthreads();

    f32x4 acc[4][4];
    #pragma unroll
    for (int r = 0; r < 4; ++r)
        #pragma unroll
        for (int c = 0; c < 4; ++c) acc[r][c] = (f32x4)0.f;

    // P1 nu half: ea[i-1] (offset 0) + ea[i] (offset 1), weight ks 8..15
    mm_tile<8, 264>(EA, 8, nw1p, wave, lane, acc);
    // early-issue p1 fragment loads (coalesced), consumed after the barrier
    unsigned int p1r[32];
    {
        const unsigned int* p1p = p1_g + ((size_t)blockIdx.x * 4 + wave) * 2048;
        #pragma unroll
        for (int i = 0; i < 32; ++i) p1r[i] = p1p[i * 64 + lane];
    }
    mm_tile<8, 264>(EA + 264, 8, nw1p, wave, lane, acc);

    float b1[4];
    #pragma unroll
    for (int c = 0; c < 4; ++c) b1[c] = nb1[(wave * 4 + c) * 16 + lrow];
    __syncthreads();  // all P1 reads of EA done
    #pragma unroll
    for (int r = 0; r < 4; ++r)
        #pragma unroll
        for (int c = 0; c < 4; ++c)
            #pragma unroll
            for (int qh = 0; qh < 2; ++qh) {
                unsigned int pk = p1r[(r * 4 + c) * 2 + qh];
                #pragma unroll
                for (int j = 0; j < 2; ++j) {
                    int q = 2 * qh + j;
                    int row = r * 16 + lkhi * 4 + q;
                    int col = (wave * 4 + c) * 16 + lrow;
                    float p1v = bfu2f(j == 0 ? (pk & 0xffffu) : (pk >> 16));
                    EA[row * 264 + col] = (bf16)silu_f(acc[r][c][q] + p1v + b1[c]);  // t4
                }
            }
    __syncthreads();

    #pragma unroll
    for (int r = 0; r < 4; ++r)
        #pragma unroll
        for (int c = 0; c < 4; ++c) acc[r][c] = (f32x4)0.f;
    mm_tile<8, 264>(EA, 0, nw2p, wave, lane, acc);
    float b2[4];
    #pragma unroll
    for (int c = 0; c < 4; ++c) b2[c] = nb2[(wave * 4 + c) * 16 + lrow];
    __syncthreads();  // all P2 reads done; overlay h_out bf16
    #pragma unroll
    for (int r = 0; r < 4; ++r)
        #pragma unroll
        for (int c = 0; c < 4; ++c)
            #pragma unroll
            for (int q = 0; q < 4; ++q) {
                int row = r * 16 + lkhi * 4 + q;
                int col = (wave * 4 + c) * 16 + lrow;
                EA[row * 264 + col] = (bf16)(acc[r][c][q] + b2[c]);
            }
    __syncthreads();
    // coalesced float2 stores of h_out
    for (int idx = tid; idx < 64 * 128; idx += 256) {
        int r = idx >> 7, cu = idx & 127;
        unsigned int v = ((const unsigned int*)&EA[r * 264])[cu];
        float2 f;
        f.x = bfu2f(v & 0xffffu);
        f.y = bfu2f(v >> 16);
        *(float2*)&h_out[(size_t)(n0 + r) * HD + 2 * cu] = f;
    }
}

// ---------------- launch ----------------
extern "C" void kernel_launch(void* const* d_in, const int* in_sizes, int n_in,
                              void* d_out, int out_size, void* d_ws, size_t ws_size,
                              hipStream_t stream) {
    const float* h   = (const float*)d_in[0];
    const float* pos = (const float*)d_in[1];
    const float* ew1 = (const float*)d_in[2];
    const float* eb1 = (const float*)d_in[3];
    const float* ew2 = (const float*)d_in[4];
    const float* eb2 = (const float*)d_in[5];
    const float* pw1 = (const float*)d_in[6];
    const float* pb1 = (const float*)d_in[7];
    const float* pw2 = (const float*)d_in[8];
    const float* nw1 = (const float*)d_in[9];
    const float* nb1 = (const float*)d_in[10];
    const float* nw2 = (const float*)d_in[11];
    const float* nb2 = (const float*)d_in[12];

    char* ws = (char*)d_ws;
    bf16*  ea   = (bf16*)ws;                      // 131072*256*2 = 67108864 B
    float* dp   = (float*)(ws + 67108864);        // 131072*3*4   = 1572864 B
    unsigned int* p1 = (unsigned int*)(ws + 68681728);  // 131072*256*2 = 67108864 B
    char*  wsw = ws + 135790592;
    bf16*  ew1p = (bf16*)(wsw);                   // 262144 B
    bf16*  ew2p = (bf16*)(wsw + 262144);          // 131072 B
    bf16*  pw1p = (bf16*)(wsw + 393216);          // 131072 B
    bf16*  nw1p = (bf16*)(wsw + 524288);          // 262144 B
    bf16*  nw2p = (bf16*)(wsw + 786432);          // 131072 B

    float* out = (float*)d_out;
    float* h_out = out;
    float* pos_out = out + (size_t)NN * HD;

    pack_kernel<<<1792, 256, 0, stream>>>(ew1, ew2, pw1, nw1, nw2,
                                          ew1p, ew2p, pw1p, nw1p, nw2p);
    edge_kernel<<<2048, 256, 0, stream>>>(h, pos, ew1, eb1, eb2, pb1, pw2,
                                          (const bf16x8*)ew1p, (const bf16x8*)ew2p,
                                          (const bf16x8*)pw1p, (const bf16x8*)nw1p,
                                          ea, p1, dp);
    node_kernel<<<2048, 256, 0, stream>>>(pos, nb1, nb2,
                                          (const bf16x8*)nw1p, (const bf16x8*)nw2p,
                                          ea, p1, dp, h_out, pos_out);
}

// Round 4
// 267.257 us; speedup vs baseline: 1.5410x; 1.4042x over previous
//
#include <hip/hip_runtime.h>
#include <hip/hip_bf16.h>
#include <math.h>

#define NN 131072
#define HD 256

typedef __bf16 bf16;
typedef __attribute__((ext_vector_type(8))) __bf16 bf16x8;
typedef __attribute__((ext_vector_type(4))) __bf16 bf16x4;
typedef __attribute__((ext_vector_type(4))) float f32x4;

__device__ __forceinline__ float silu_f(float x) { return x / (1.f + __expf(-x)); }

__device__ __forceinline__ float bfu2f(unsigned int lo16) {
    unsigned int u = lo16 << 16;
    return __builtin_bit_cast(float, u);
}
__device__ __forceinline__ unsigned short f2bfu(float f) {
    bf16 b = (bf16)f;
    return __builtin_bit_cast(unsigned short, b);
}

// A-tile (LDS bf16, row stride LDA) x packed-B (global bf16x8, weight k-step offset bk0)
template<int KSTEPS, int LDA>
__device__ __forceinline__ void mm_tile(const bf16* Xl, int bk0, const bf16x8* __restrict__ Bp,
                                        int wave, int lane, f32x4 acc[4][4]) {
    const int lrow = lane & 15, lkhi = lane >> 4;
    #pragma unroll
    for (int ks = 0; ks < KSTEPS; ++ks) {
        bf16x8 a[4];
        #pragma unroll
        for (int r = 0; r < 4; ++r)
            a[r] = *(const bf16x8*)&Xl[(r * 16 + lrow) * LDA + ks * 32 + lkhi * 8];
        #pragma unroll
        for (int c = 0; c < 4; ++c) {
            bf16x8 b = Bp[((bk0 + ks) * 16 + wave * 4 + c) * 64 + lane];
            #pragma unroll
            for (int r = 0; r < 4; ++r)
                acc[r][c] = __builtin_amdgcn_mfma_f32_16x16x32_bf16(a[r], b, acc[r][c], 0, 0, 0);
        }
    }
}

// ---------------- weight packing ----------------
__device__ __forceinline__ void packW(const float* __restrict__ W, bf16* __restrict__ P, int idx) {
    int j  = idx & 7;
    int ln = (idx >> 3) & 63;
    int cb = (idx >> 9) & 15;
    int ks = idx >> 13;
    int k = ks * 32 + ((ln >> 4) << 3) + j;
    int n = (cb << 4) + (ln & 15);
    P[idx] = (bf16)W[k * HD + n];
}

__global__ void pack_kernel(const float* __restrict__ ew1, const float* __restrict__ ew2,
                            const float* __restrict__ pw1, const float* __restrict__ nw1,
                            const float* __restrict__ nw2,
                            bf16* __restrict__ ew1p, bf16* __restrict__ ew2p,
                            bf16* __restrict__ pw1p, bf16* __restrict__ nw1p,
                            bf16* __restrict__ nw2p) {
    int t = blockIdx.x * 256 + threadIdx.x;
    if (t < 131072) { packW(ew1, ew1p, t); return; }
    t -= 131072;
    if (t < 65536)  { packW(ew2, ew2p, t); return; }
    t -= 65536;
    if (t < 65536)  { packW(pw1, pw1p, t); return; }
    t -= 65536;
    if (t < 131072) { packW(nw1, nw1p, t); return; }
    t -= 131072;
    if (t < 65536)  { packW(nw2, nw2p, t); return; }
}

// ---------------- edge kernel ----------------
// 64 edges/block, single LDS buffer, 4 blocks/CU.
// Computes: p1 = h@nw1[:256] (fragment layout), ea chain, q1 = ea@nw1[256:] (row
// layout), dp. ea itself is never written to global.
__global__ __launch_bounds__(256, 4) void edge_kernel(
    const float* __restrict__ h, const float* __restrict__ pos,
    const float* __restrict__ ew1, const float* __restrict__ eb1,
    const float* __restrict__ eb2, const float* __restrict__ pb1,
    const float* __restrict__ pw2,
    const bf16x8* __restrict__ ew1p, const bf16x8* __restrict__ ew2p,
    const bf16x8* __restrict__ pw1p, const bf16x8* __restrict__ nw1p,
    bf16* __restrict__ q1_g, uint2* __restrict__ p1_g,
    float* __restrict__ dp_g) {
    __shared__ bf16 X[65 * 264];          // h rows -> t1 -> ea -> q1 (in place)
    __shared__ float dist_s[64];
    __shared__ float dp_s[4][64][3];

    const int tid = threadIdx.x;
    const int lane = tid & 63, wave = tid >> 6;
    const int lrow = lane & 15, lkhi = lane >> 4;
    const int e0 = blockIdx.x * 64;

    // stage h rows e0..e0+64 (bf16)
    for (int idx = tid; idx < 65 * 64; idx += 256) {
        int r = idx >> 6, c4 = (idx & 63) << 2;
        int gr = e0 + r;
        float4 v = make_float4(0.f, 0.f, 0.f, 0.f);
        if (gr < NN) v = *(const float4*)&h[(size_t)gr * HD + c4];
        bf16x4 b;
        b[0] = (bf16)v.x; b[1] = (bf16)v.y; b[2] = (bf16)v.z; b[3] = (bf16)v.w;
        *(bf16x4*)&X[r * 264 + c4] = b;
    }
    if (tid < 64) {
        int e = e0 + tid;
        float d = 0.f;
        if (e < NN - 1) {
            float dx = pos[3 * e + 3] - pos[3 * e];
            float dy = pos[3 * e + 4] - pos[3 * e + 1];
            float dz = pos[3 * e + 5] - pos[3 * e + 2];
            d = sqrtf(dx * dx + dy * dy + dz * dz);
        }
        dist_s[tid] = d;
    }
    __syncthreads();

    f32x4 acc[4][4];

    // phase 0: p1 = h_tile @ nw1[0:256] -> p1_g (uint2, fragment layout)
    #pragma unroll
    for (int r = 0; r < 4; ++r)
        #pragma unroll
        for (int c = 0; c < 4; ++c) acc[r][c] = (f32x4)0.f;
    mm_tile<8, 264>(X, 0, nw1p, wave, lane, acc);
    {
        uint2* p1w = p1_g + ((size_t)blockIdx.x * 4 + wave) * 1024;
        #pragma unroll
        for (int r = 0; r < 4; ++r)
            #pragma unroll
            for (int c = 0; c < 4; ++c) {
                uint2 v;
                v.x = (unsigned int)f2bfu(acc[r][c][0]) | ((unsigned int)f2bfu(acc[r][c][1]) << 16);
                v.y = (unsigned int)f2bfu(acc[r][c][2]) | ((unsigned int)f2bfu(acc[r][c][3]) << 16);
                p1w[(r * 4 + c) * 64 + lane] = v;
            }
    }

    // phase 1: t1 = silu(edge_feat @ ew1 + eb1); K halves via row shift rb
    #pragma unroll
    for (int r = 0; r < 4; ++r)
        #pragma unroll
        for (int c = 0; c < 4; ++c) acc[r][c] = (f32x4)0.f;
    #pragma unroll
    for (int ks = 0; ks < 16; ++ks) {
        const int rb = (ks >= 8) ? 1 : 0;
        const int kk = ks * 32 + lkhi * 8 - rb * 256;
        bf16x8 a[4];
        #pragma unroll
        for (int r = 0; r < 4; ++r)
            a[r] = *(const bf16x8*)&X[(r * 16 + lrow + rb) * 264 + kk];
        #pragma unroll
        for (int c = 0; c < 4; ++c) {
            bf16x8 b = ew1p[(ks * 16 + wave * 4 + c) * 64 + lane];
            #pragma unroll
            for (int r = 0; r < 4; ++r)
                acc[r][c] = __builtin_amdgcn_mfma_f32_16x16x32_bf16(a[r], b, acc[r][c], 0, 0, 0);
        }
    }
    float bias1[4], wlast[4], w2l[4][3];
    #pragma unroll
    for (int c = 0; c < 4; ++c) {
        int col = (wave * 4 + c) * 16 + lrow;
        bias1[c] = eb1[col];
        wlast[c] = ew1[512 * HD + col];       // dist row of ew1
        #pragma unroll
        for (int x = 0; x < 3; ++x) w2l[c][x] = pw2[col * 3 + x];
    }
    __syncthreads();  // all phase-0/1 reads of X done
    #pragma unroll
    for (int r = 0; r < 4; ++r)
        #pragma unroll
        for (int c = 0; c < 4; ++c)
            #pragma unroll
            for (int q = 0; q < 4; ++q) {
                int row = r * 16 + lkhi * 4 + q;
                int col = (wave * 4 + c) * 16 + lrow;
                float v = acc[r][c][q] + dist_s[row] * wlast[c] + bias1[c];
                X[row * 264 + col] = (bf16)silu_f(v);  // t1 in place
            }
    __syncthreads();

    // phase 2: ea = t1 @ ew2 + eb2 (in place)
    #pragma unroll
    for (int r = 0; r < 4; ++r)
        #pragma unroll
        for (int c = 0; c < 4; ++c) acc[r][c] = (f32x4)0.f;
    mm_tile<8, 264>(X, 0, ew2p, wave, lane, acc);
    float bias2[4];
    #pragma unroll
    for (int c = 0; c < 4; ++c) bias2[c] = eb2[(wave * 4 + c) * 16 + lrow];
    __syncthreads();
    #pragma unroll
    for (int r = 0; r < 4; ++r)
        #pragma unroll
        for (int c = 0; c < 4; ++c)
            #pragma unroll
            for (int q = 0; q < 4; ++q) {
                int row = r * 16 + lkhi * 4 + q;
                int col = (wave * 4 + c) * 16 + lrow;
                X[row * 264 + col] = (bf16)(acc[r][c][q] + bias2[c]);  // ea in place
            }
    __syncthreads();

    // phase 3a: t3 = silu(ea @ pw1 + pb1) in regs; dp = t3 @ pw2 reduced
    #pragma unroll
    for (int r = 0; r < 4; ++r)
        #pragma unroll
        for (int c = 0; c < 4; ++c) acc[r][c] = (f32x4)0.f;
    mm_tile<8, 264>(X, 0, pw1p, wave, lane, acc);
    float bias3[4];
    #pragma unroll
    for (int c = 0; c < 4; ++c) bias3[c] = pb1[(wave * 4 + c) * 16 + lrow];

    #pragma unroll
    for (int r = 0; r < 4; ++r) {
        float red[12];
        #pragma unroll
        for (int q = 0; q < 4; ++q) {
            float t3v[4];
            #pragma unroll
            for (int c = 0; c < 4; ++c) t3v[c] = silu_f(acc[r][c][q] + bias3[c]);
            #pragma unroll
            for (int x = 0; x < 3; ++x) {
                float s = 0.f;
                #pragma unroll
                for (int c = 0; c < 4; ++c) s += t3v[c] * w2l[c][x];
                red[q * 3 + x] = s;
            }
        }
        #pragma unroll
        for (int i = 0; i < 12; ++i) {
            float v = red[i];
            v += __shfl_xor(v, 1);
            v += __shfl_xor(v, 2);
            v += __shfl_xor(v, 4);
            v += __shfl_xor(v, 8);
            red[i] = v;
        }
        if (lrow == 0) {
            #pragma unroll
            for (int q = 0; q < 4; ++q)
                #pragma unroll
                for (int x = 0; x < 3; ++x)
                    dp_s[wave][r * 16 + lkhi * 4 + q][x] = red[q * 3 + x];
        }
    }

    // phase 3b: q1 = ea @ nw1[256:512] (reads same X state as pw1 — no barrier)
    #pragma unroll
    for (int r = 0; r < 4; ++r)
        #pragma unroll
        for (int c = 0; c < 4; ++c) acc[r][c] = (f32x4)0.f;
    mm_tile<8, 264>(X, 8, nw1p, wave, lane, acc);

    __syncthreads();  // all X reads done + dp_s visible
    // overlay X = q1
    #pragma unroll
    for (int r = 0; r < 4; ++r)
        #pragma unroll
        for (int c = 0; c < 4; ++c)
            #pragma unroll
            for (int q = 0; q < 4; ++q) {
                int row = r * 16 + lkhi * 4 + q;
                int col = (wave * 4 + c) * 16 + lrow;
                X[row * 264 + col] = (bf16)acc[r][c][q];
            }
    if (tid < 192) {
        int row = tid / 3, x = tid - row * 3;
        float s = dp_s[0][row][x] + dp_s[1][row][x] + dp_s[2][row][x] + dp_s[3][row][x];
        dp_g[(size_t)(e0 + row) * 3 + x] = s;
    }
    __syncthreads();
    // q1 -> global (row layout, coalesced)
    for (int idx = tid; idx < 64 * 128; idx += 256) {
        int r = idx >> 7, cu = idx & 127;
        ((unsigned int*)&q1_g[(size_t)(e0 + r) * HD])[cu] = ((const unsigned int*)&X[r * 264])[cu];
    }
}

// ---------------- node kernel ----------------
// t4 = silu(p1[i] + q1[i] + q1[i-1] + nb1); h_out = t4 @ nw2 + nb2.
// Only one 128-MFMA GEMM; q1 halo staged 16B-coalesced; p1 read as uint2 fragments.
__global__ __launch_bounds__(256, 4) void node_kernel(
    const float* __restrict__ pos,
    const float* __restrict__ nb1, const float* __restrict__ nb2,
    const bf16x8* __restrict__ nw2p,
    const bf16* __restrict__ q1_g, const uint2* __restrict__ p1_g,
    const float* __restrict__ dp_g,
    float* __restrict__ h_out, float* __restrict__ pos_out) {
    __shared__ bf16 X[65 * 264];   // q1 halo (slot t = q1[n0-1+t]) -> t4 rows 0..63

    const int tid = threadIdx.x;
    const int lane = tid & 63, wave = tid >> 6;
    const int lrow = lane & 15, lkhi = lane >> 4;
    const int n0 = blockIdx.x * 64;

    // pos head
    if (tid < 192) {
        int row = tid & 63, col = tid >> 6;
        int i = n0 + row;
        float dpi = (i < NN - 1) ? dp_g[(size_t)i * 3 + col] : 0.f;
        float dpm = (i > 0) ? dp_g[(size_t)(i - 1) * 3 + col] : 0.f;
        pos_out[(size_t)i * 3 + col] = pos[(size_t)i * 3 + col] + 0.1f * (dpi - dpm);
    }

    // stage q1 halo, uint4-vectorized (row = 512B = 32 uint4)
    for (int idx = tid; idx < 65 * 32; idx += 256) {
        int t = idx >> 5, cu = idx & 31;
        int er = n0 - 1 + t;
        uint4 v = make_uint4(0u, 0u, 0u, 0u);
        if (er >= 0 && er <= NN - 2) v = ((const uint4*)&q1_g[(size_t)er * HD])[cu];
        ((uint4*)&X[t * 264])[cu] = v;
    }
    // early p1 fragment loads (coalesced uint2)
    uint2 p1r[16];
    {
        const uint2* p1p = p1_g + ((size_t)blockIdx.x * 4 + wave) * 1024;
        #pragma unroll
        for (int i = 0; i < 16; ++i) p1r[i] = p1p[i * 64 + lane];
    }
    float b1[4];
    #pragma unroll
    for (int c = 0; c < 4; ++c) b1[c] = nb1[(wave * 4 + c) * 16 + lrow];
    __syncthreads();

    // elementwise t4 = silu(p1 + q1[i] + q1[i-1] + b1), held in regs
    unsigned int t4p[32];
    #pragma unroll
    for (int r = 0; r < 4; ++r)
        #pragma unroll
        for (int c = 0; c < 4; ++c) {
            int i = r * 4 + c;
            int col = (wave * 4 + c) * 16 + lrow;
            #pragma unroll
            for (int qh = 0; qh < 2; ++qh) {
                unsigned int pk = qh == 0 ? p1r[i].x : p1r[i].y;
                unsigned int outp = 0;
                #pragma unroll
                for (int j = 0; j < 2; ++j) {
                    int q = 2 * qh + j;
                    int row = r * 16 + lkhi * 4 + q;
                    float p1v = bfu2f(j == 0 ? (pk & 0xffffu) : (pk >> 16));
                    float z = p1v + (float)X[(row + 1) * 264 + col] + (float)X[row * 264 + col] + b1[c];
                    unsigned short tb = f2bfu(silu_f(z));
                    outp |= (unsigned int)tb << (16 * j);
                }
                t4p[i * 2 + qh] = outp;
            }
        }
    __syncthreads();  // all q1 reads done
    // write t4 tile (rows 0..63)
    #pragma unroll
    for (int r = 0; r < 4; ++r)
        #pragma unroll
        for (int c = 0; c < 4; ++c) {
            int i = r * 4 + c;
            int col = (wave * 4 + c) * 16 + lrow;
            #pragma unroll
            for (int q = 0; q < 4; ++q) {
                int row = r * 16 + lkhi * 4 + q;
                unsigned int pk = t4p[i * 2 + (q >> 1)];
                unsigned short tb = (unsigned short)((q & 1) ? (pk >> 16) : (pk & 0xffffu));
                X[row * 264 + col] = __builtin_bit_cast(bf16, tb);
            }
        }
    __syncthreads();

    // P2: h_out = t4 @ nw2 + nb2, direct 64B-sector-aligned stores
    f32x4 acc[4][4];
    #pragma unroll
    for (int r = 0; r < 4; ++r)
        #pragma unroll
        for (int c = 0; c < 4; ++c) acc[r][c] = (f32x4)0.f;
    mm_tile<8, 264>(X, 0, nw2p, wave, lane, acc);
    float b2[4];
    #pragma unroll
    for (int c = 0; c < 4; ++c) b2[c] = nb2[(wave * 4 + c) * 16 + lrow];
    #pragma unroll
    for (int r = 0; r < 4; ++r)
        #pragma unroll
        for (int c = 0; c < 4; ++c)
            #pragma unroll
            for (int q = 0; q < 4; ++q) {
                int row = r * 16 + lkhi * 4 + q;
                int col = (wave * 4 + c) * 16 + lrow;
                h_out[(size_t)(n0 + row) * HD + col] = acc[r][c][q] + b2[c];
            }
}

// ---------------- launch ----------------
extern "C" void kernel_launch(void* const* d_in, const int* in_sizes, int n_in,
                              void* d_out, int out_size, void* d_ws, size_t ws_size,
                              hipStream_t stream) {
    const float* h   = (const float*)d_in[0];
    const float* pos = (const float*)d_in[1];
    const float* ew1 = (const float*)d_in[2];
    const float* eb1 = (const float*)d_in[3];
    const float* ew2 = (const float*)d_in[4];
    const float* eb2 = (const float*)d_in[5];
    const float* pw1 = (const float*)d_in[6];
    const float* pb1 = (const float*)d_in[7];
    const float* pw2 = (const float*)d_in[8];
    const float* nw1 = (const float*)d_in[9];
    const float* nb1 = (const float*)d_in[10];
    const float* nw2 = (const float*)d_in[11];
    const float* nb2 = (const float*)d_in[12];

    char* ws = (char*)d_ws;
    bf16*  q1   = (bf16*)ws;                      // 131072*256*2 = 67108864 B
    float* dp   = (float*)(ws + 67108864);        // 131072*3*4   = 1572864 B
    uint2* p1   = (uint2*)(ws + 68681728);        // 131072*256*2 = 67108864 B
    char*  wsw = ws + 135790592;
    bf16*  ew1p = (bf16*)(wsw);                   // 262144 B
    bf16*  ew2p = (bf16*)(wsw + 262144);          // 131072 B
    bf16*  pw1p = (bf16*)(wsw + 393216);          // 131072 B
    bf16*  nw1p = (bf16*)(wsw + 524288);          // 262144 B
    bf16*  nw2p = (bf16*)(wsw + 786432);          // 131072 B

    float* out = (float*)d_out;
    float* h_out = out;
    float* pos_out = out + (size_t)NN * HD;

    pack_kernel<<<1792, 256, 0, stream>>>(ew1, ew2, pw1, nw1, nw2,
                                          ew1p, ew2p, pw1p, nw1p, nw2p);
    edge_kernel<<<2048, 256, 0, stream>>>(h, pos, ew1, eb1, eb2, pb1, pw2,
                                          (const bf16x8*)ew1p, (const bf16x8*)ew2p,
                                          (const bf16x8*)pw1p, (const bf16x8*)nw1p,
                                          q1, p1, dp);
    node_kernel<<<2048, 256, 0, stream>>>(pos, nb1, nb2,
                                          (const bf16x8*)nw2p,
                                          q1, (const uint2*)p1, dp, h_out, pos_out);
}